// Round 5
// baseline (336.193 us; speedup 1.0000x reference)
//
#include <hip/hip_runtime.h>
#include <stdint.h>

// ---------------------------------------------------------------------------
// MultiHeadAttentionWithRelativePosition  (B=8, H=16, L=768, D=1024, dk=64)
// R5: 256x128 GEMM block tiles (32 MFMA per barrier vs 16) + XCD-local A
// mapping (per-XCD L2 footprint ~3.5MB). Attn/cast unchanged from R4.
// ---------------------------------------------------------------------------

#define DEVFN static __device__ __forceinline__

typedef __bf16 bf16x8 __attribute__((ext_vector_type(8)));
typedef float f32x4 __attribute__((ext_vector_type(4)));

DEVFN uint16_t f2bf(float f) {
  uint32_t u = __builtin_bit_cast(uint32_t, f);
  u += 0x7fffu + ((u >> 16) & 1u);   // RNE
  return (uint16_t)(u >> 16);
}
DEVFN bf16x8 ldg8(const uint16_t* p) { return *reinterpret_cast<const bf16x8*>(p); }

DEVFN void load_lds16(const void* g, void* l) {
  __builtin_amdgcn_global_load_lds((const __attribute__((address_space(1))) uint32_t*)g,
                                   (__attribute__((address_space(3))) uint32_t*)l,
                                   16, 0, 0);
}

DEVFN float bperm(int addr, float v) {
  return __builtin_bit_cast(float,
      __builtin_amdgcn_ds_bpermute(addr, __builtin_bit_cast(int, v)));
}

#define MFMA __builtin_amdgcn_mfma_f32_16x16x32_bf16

// ---------------- workspace layout (uint16 element offsets) ----------------
static const size_t OXQ = 0;
static const size_t OXK = 6291456;
static const size_t OXV = 12582912;
static const size_t OWQ = 18874368;
static const size_t OWK = 19922944;
static const size_t OWV = 20971520;
static const size_t OWO = 22020096;
static const size_t OEB = 23068672;   // 98304 elems (frag-linear E, 96 tiles)
static const size_t OQH = 23166976;
static const size_t OKH = 29458432;
static const size_t OVT = 35749888;
static const size_t OAO = 42041344;

// ------------------------------ cast kernel --------------------------------
__global__ __launch_bounds__(256) void cast_kernel(
    const float* __restrict__ q, const float* __restrict__ k, const float* __restrict__ v,
    const float* __restrict__ wq, const float* __restrict__ wk, const float* __restrict__ wv,
    const float* __restrict__ wo, const float* __restrict__ e, uint16_t* __restrict__ ws)
{
  constexpr int NQ = 6291456 / 4, NW = 1048576 / 4;
  constexpr int TOTM = 3 * NQ + 4 * NW;
  constexpr int NE4 = 98304 / 4;
  for (int i = blockIdx.x * blockDim.x + threadIdx.x; i < TOTM + NE4;
       i += gridDim.x * blockDim.x) {
    if (i < TOTM) {
      const float* src; uint16_t* dst; int off = i;
      if (off < NQ)              { src = q;  dst = ws + OXQ; }
      else if ((off -= NQ) < NQ) { src = k;  dst = ws + OXK; }
      else if ((off -= NQ) < NQ) { src = v;  dst = ws + OXV; }
      else if ((off -= NQ) < NW) { src = wq; dst = ws + OWQ; }
      else if ((off -= NW) < NW) { src = wk; dst = ws + OWK; }
      else if ((off -= NW) < NW) { src = wv; dst = ws + OWV; }
      else { off -= NW;            src = wo; dst = ws + OWO; }
      float4 f = reinterpret_cast<const float4*>(src)[off];
      ushort4 u;
      u.x = f2bf(f.x); u.y = f2bf(f.y); u.z = f2bf(f.z); u.w = f2bf(f.w);
      reinterpret_cast<ushort4*>(dst)[off] = u;
    } else {
      // fragment-linear E: tile tau covers rel rows [16*tau, 16*tau+15]
      int e4 = i - TOTM;
      ushort4 u;
#pragma unroll
      for (int t = 0; t < 4; ++t) {
        int o = e4 * 4 + t;
        int tau = o >> 10, r10 = o & 1023;
        int c = r10 >> 9, lane = (r10 >> 3) & 63, j = o & 7;
        int row = tau * 16 + (lane & 15);
        row = row > 1534 ? 1534 : row;
        int col = c * 32 + (lane >> 4) * 8 + j;
        ((uint16_t*)&u)[t] = f2bf(e[row * 64 + col]);
      }
      reinterpret_cast<ushort4*>(ws + OEB)[e4] = u;
    }
  }
}

// --------------------- fused QKV projection GEMM (256x128 tiles) -----------
// 576 blocks: [0,192) Q-proj, [192,384) K-proj, [384,576) V^T.
// XCD-local decode: x = t&7 (== XCD under round-robin), A slice L2-resident.
__global__ __launch_bounds__(256, 2) void gemm_qkv(
    uint16_t* __restrict__ ws, const float* __restrict__ bq,
    const float* __restrict__ bk, const float* __restrict__ bv)
{
  constexpr int K = 1024;
  __shared__ uint16_t As[256 * 32];   // 16 KB
  __shared__ uint16_t Bs[128 * 32];   // 8 KB
  const int f = blockIdx.x;
  const int mode = f / 192, t = f % 192;
  const int x = t & 7, u6 = t >> 3;   // u6 in [0,24)
  const uint16_t *A, *Bw; const float* bias; uint16_t* outp;
  int m0, n0;
  if (mode == 0)      { A = ws + OXQ; Bw = ws + OWQ; bias = bq; outp = ws + OQH;
                        m0 = (x * 3 + u6 % 3) * 256; n0 = (u6 / 3) * 128; }
  else if (mode == 1) { A = ws + OXK; Bw = ws + OWK; bias = bk; outp = ws + OKH;
                        m0 = (x * 3 + u6 % 3) * 256; n0 = (u6 / 3) * 128; }
  else                { A = ws + OWV; Bw = ws + OXV; bias = bv; outp = ws + OVT;
                        m0 = (u6 / 6) * 256; n0 = (x * 6 + u6 % 6) * 128; }

  const int tid = threadIdx.x, wave = tid >> 6, lane = tid & 63;
  const int quad = lane >> 4, lc = lane & 15;
  const int wm = (wave >> 1) * 128, wn = (wave & 1) * 64;
  const int srow = lane >> 2, schunk = (lane & 3) * 8;

  f32x4 acc[8][4];
#pragma unroll
  for (int i = 0; i < 8; ++i)
#pragma unroll
    for (int j = 0; j < 4; ++j) acc[i][j] = (f32x4){0.f, 0.f, 0.f, 0.f};

  for (int k0 = 0; k0 < K; k0 += 32) {
    __syncthreads();
#pragma unroll
    for (int j = 0; j < 4; ++j) {
      int r = wave * 64 + j * 16 + srow;
      load_lds16(A + (size_t)(m0 + r) * K + k0 + schunk, &As[(wave * 64 + j * 16) * 32]);
    }
#pragma unroll
    for (int j = 0; j < 2; ++j) {
      int r = wave * 32 + j * 16 + srow;
      load_lds16(Bw + (size_t)(n0 + r) * K + k0 + schunk, &Bs[(wave * 32 + j * 16) * 32]);
    }
    __syncthreads();
    bf16x8 af[8], bfr[4];
#pragma unroll
    for (int u = 0; u < 8; ++u)
      af[u]  = *reinterpret_cast<const bf16x8*>(&As[(wm + u * 16 + lc) * 32 + quad * 8]);
#pragma unroll
    for (int u = 0; u < 4; ++u)
      bfr[u] = *reinterpret_cast<const bf16x8*>(&Bs[(wn + u * 16 + lc) * 32 + quad * 8]);
#pragma unroll
    for (int i = 0; i < 8; ++i)
#pragma unroll
      for (int j = 0; j < 4; ++j)
        acc[i][j] = MFMA(af[i], bfr[j], acc[i][j], 0, 0, 0);
  }

  const int bM = (m0 + wm) / 768;   // wave's 128-row span never straddles 768
  const int bN = n0 / 768;
#pragma unroll
  for (int i = 0; i < 8; ++i)
#pragma unroll
    for (int j = 0; j < 4; ++j)
#pragma unroll
      for (int r = 0; r < 4; ++r) {
        int mg = m0 + wm + i * 16 + quad * 4 + r;
        int ng = n0 + wn + j * 16 + lc;
        float v = acc[i][j][r];
        if (mode == 0) {
          v = (v + bias[ng]) * 0.125f;         // 1/sqrt(64) folded into Q
          int lr = mg - bM * 768;
          int h = ng >> 6, d = ng & 63;
          outp[(((size_t)(bM * 16 + h) * 768 + lr) << 6) + d] = f2bf(v);
        } else if (mode == 1) {
          // frag-linear K
          v += bias[ng];
          int lr = mg - bM * 768;
          int h = ng >> 6, d = ng & 63;
          size_t flat = ((size_t)(bM * 16 + h) * 48 + (lr >> 4)) * 1024
                      + ((size_t)(d >> 5) << 9)
                      + ((((d >> 3) & 3) * 16 + (lr & 15)) << 3) + (d & 7);
          outp[flat] = f2bf(v);
        } else {
          // frag-linear V
          v += bias[mg];
          int lr = ng - bN * 768;
          int h = mg >> 6, d = mg & 63;
          size_t flat = (size_t)(bN * 16 + h) * 49152
                      + (size_t)(lr >> 5) * 2048 + (size_t)(d >> 4) * 512
                      + ((((lr >> 3) & 3) * 16 + (d & 15)) << 3) + (lr & 7);
          outp[flat] = f2bf(v);
        }
      }
}

// ------------------------- O-projection GEMM (256x128 tiles) ---------------
// 192 blocks; XCD x owns batch x rows of Ao (A L2-resident) + full Wo.
__global__ __launch_bounds__(256, 2) void gemm_o(
    const uint16_t* __restrict__ A, const uint16_t* __restrict__ Bw,
    const float* __restrict__ bias, float* __restrict__ outp)
{
  constexpr int K = 1024;
  __shared__ uint16_t As[256 * 32];
  __shared__ uint16_t Bs[128 * 32];
  const int t = blockIdx.x;
  const int x = t & 7, u6 = t >> 3;
  const int m0 = (x * 3 + u6 % 3) * 256, n0 = (u6 / 3) * 128;

  const int tid = threadIdx.x, wave = tid >> 6, lane = tid & 63;
  const int quad = lane >> 4, lc = lane & 15;
  const int wm = (wave >> 1) * 128, wn = (wave & 1) * 64;
  const int srow = lane >> 2, schunk = (lane & 3) * 8;

  f32x4 acc[8][4];
#pragma unroll
  for (int i = 0; i < 8; ++i)
#pragma unroll
    for (int j = 0; j < 4; ++j) acc[i][j] = (f32x4){0.f, 0.f, 0.f, 0.f};

  for (int k0 = 0; k0 < K; k0 += 32) {
    __syncthreads();
#pragma unroll
    for (int j = 0; j < 4; ++j) {
      int r = wave * 64 + j * 16 + srow;
      load_lds16(A + (size_t)(m0 + r) * K + k0 + schunk, &As[(wave * 64 + j * 16) * 32]);
    }
#pragma unroll
    for (int j = 0; j < 2; ++j) {
      int r = wave * 32 + j * 16 + srow;
      load_lds16(Bw + (size_t)(n0 + r) * K + k0 + schunk, &Bs[(wave * 32 + j * 16) * 32]);
    }
    __syncthreads();
    bf16x8 af[8], bfr[4];
#pragma unroll
    for (int u = 0; u < 8; ++u)
      af[u]  = *reinterpret_cast<const bf16x8*>(&As[(wm + u * 16 + lc) * 32 + quad * 8]);
#pragma unroll
    for (int u = 0; u < 4; ++u)
      bfr[u] = *reinterpret_cast<const bf16x8*>(&Bs[(wn + u * 16 + lc) * 32 + quad * 8]);
#pragma unroll
    for (int i = 0; i < 8; ++i)
#pragma unroll
      for (int j = 0; j < 4; ++j)
        acc[i][j] = MFMA(af[i], bfr[j], acc[i][j], 0, 0, 0);
  }

#pragma unroll
  for (int i = 0; i < 8; ++i)
#pragma unroll
    for (int j = 0; j < 4; ++j)
#pragma unroll
      for (int r = 0; r < 4; ++r) {
        int mg = m0 + wm + i * 16 + quad * 4 + r;
        int ng = n0 + wn + j * 16 + lc;
        outp[(size_t)mg * 1024 + ng] = acc[i][j][r] + bias[ng];
      }
}

// ------------------------------ attention (flash) --------------------------
// Unchanged from R4 (frag-linear K/V/E; verified).
__global__ __launch_bounds__(256, 3) void attn_kernel(
    const uint16_t* __restrict__ Qh, const uint16_t* __restrict__ KTf,
    const uint16_t* __restrict__ VTf, const uint16_t* __restrict__ Et,
    uint16_t* __restrict__ Ao)
{
  constexpr int L = 768, DK = 64;
  __shared__ uint16_t Pb[4][16][40];
  const int wave = threadIdx.x >> 6, lane = threadIdx.x & 63;
  const int quad = lane >> 4, lc = lane & 15;
  const int f = blockIdx.x, g = f >> 3;
  const int bh = (f & 7) * 16 + (g & 15);
  const int q0 = ((g >> 4) * 4 + wave) * 16;
  const int lane8 = lane * 8;

  const uint16_t* Qp = Qh + ((size_t)bh * L + q0) * DK;
  bf16x8 qf0 = ldg8(Qp + lc * DK + quad * 8);
  bf16x8 qf1 = ldg8(Qp + lc * DK + 32 + quad * 8);

  int addr_r[4]; bool sel_r[4];
#pragma unroll
  for (int r = 0; r < 4; ++r) {
    int qi = quad * 4 + r;
    int t = lc - qi + 15;
    addr_r[r] = (quad * 16 + (t & 15)) * 4;
    sel_r[r] = t >= 16;
  }

  float l_r[4] = {0.f, 0.f, 0.f, 0.f};
  f32x4 o[4];
#pragma unroll
  for (int t = 0; t < 4; ++t) o[t] = (f32x4){0.f, 0.f, 0.f, 0.f};

  const uint16_t* Kb = KTf + (size_t)bh * 48 * 1024;
  const uint16_t* Vb = VTf + (size_t)bh * 49152;
  const int taubase = 47 - (q0 >> 4);

#pragma unroll 1
  for (int kb = 0; kb < 24; ++kb) {
    const uint16_t* kp = Kb + (size_t)(2 * kb) * 1024 + lane8;
    bf16x8 k0a = ldg8(kp),        k0b = ldg8(kp + 512);
    bf16x8 k1a = ldg8(kp + 1024), k1b = ldg8(kp + 1536);
    const uint16_t* vp = Vb + (size_t)kb * 2048 + lane8;
    bf16x8 vf0 = ldg8(vp), vf1 = ldg8(vp + 512), vf2 = ldg8(vp + 1024), vf3 = ldg8(vp + 1536);

    f32x4 s0 = (f32x4){0.f, 0.f, 0.f, 0.f}, s1 = s0;
    s0 = MFMA(qf0, k0a, s0, 0, 0, 0);
    s0 = MFMA(qf1, k0b, s0, 0, 0, 0);
    s1 = MFMA(qf0, k1a, s1, 0, 0, 0);
    s1 = MFMA(qf1, k1b, s1, 0, 0, 0);

    f32x4 w[3];
#pragma unroll
    for (int ww = 0; ww < 3; ++ww) {
      const uint16_t* ep = Et + (size_t)(taubase + 2 * kb + ww) * 1024 + lane8;
      bf16x8 e0 = ldg8(ep), e1 = ldg8(ep + 512);
      f32x4 a = (f32x4){0.f, 0.f, 0.f, 0.f};
      a = MFMA(qf0, e0, a, 0, 0, 0);
      a = MFMA(qf1, e1, a, 0, 0, 0);
      w[ww] = a;
    }

#pragma unroll
    for (int r = 0; r < 4; ++r) {
      float v0a  = bperm(addr_r[r], w[0][r]);
      float vmid = bperm(addr_r[r], w[1][r]);
      float v1b  = bperm(addr_r[r], w[2][r]);
      float e0 = __expf(s0[r] + (sel_r[r] ? vmid : v0a));
      float e1 = __expf(s1[r] + (sel_r[r] ? v1b : vmid));
      l_r[r] += e0 + e1;
      int qi = quad * 4 + r;
      Pb[wave][qi][lc]      = f2bf(e0);
      Pb[wave][qi][16 + lc] = f2bf(e1);
    }

    __builtin_amdgcn_s_waitcnt(0xC07F);   // lgkmcnt(0), wave-local

    bf16x8 af = *reinterpret_cast<const bf16x8*>(&Pb[wave][lc][quad * 8]);
    o[0] = MFMA(af, vf0, o[0], 0, 0, 0);
    o[1] = MFMA(af, vf1, o[1], 0, 0, 0);
    o[2] = MFMA(af, vf2, o[2], 0, 0, 0);
    o[3] = MFMA(af, vf3, o[3], 0, 0, 0);
  }

#pragma unroll
  for (int r = 0; r < 4; ++r) {
    float l = l_r[r];
    l += __shfl_xor(l, 1, 64);
    l += __shfl_xor(l, 2, 64);
    l += __shfl_xor(l, 4, 64);
    l += __shfl_xor(l, 8, 64);
    l_r[r] = 1.0f / l;
  }

  const int b = bh >> 4, h = bh & 15;
#pragma unroll
  for (int r = 0; r < 4; ++r) {
    int qi = quad * 4 + r;
    size_t bse = ((size_t)b * L + (q0 + qi)) * 1024 + h * 64;
#pragma unroll
    for (int nt = 0; nt < 4; ++nt)
      Ao[bse + nt * 16 + lc] = f2bf(o[nt][r] * l_r[r]);
  }
}

// ------------------------------ launcher -----------------------------------
extern "C" void kernel_launch(void* const* d_in, const int* in_sizes, int n_in,
                              void* d_out, int out_size, void* d_ws, size_t ws_size,
                              hipStream_t stream) {
  const float* q   = (const float*)d_in[0];
  const float* k   = (const float*)d_in[1];
  const float* v   = (const float*)d_in[2];
  const float* b_q = (const float*)d_in[4];
  const float* b_k = (const float*)d_in[6];
  const float* b_v = (const float*)d_in[8];
  const float* b_o = (const float*)d_in[10];
  uint16_t* ws = (uint16_t*)d_ws;

  cast_kernel<<<4096, 256, 0, stream>>>(q, k, v,
      (const float*)d_in[3], (const float*)d_in[5], (const float*)d_in[7],
      (const float*)d_in[9], (const float*)d_in[11], ws);

  gemm_qkv<<<576, 256, 0, stream>>>(ws, b_q, b_k, b_v);

  attn_kernel<<<1536, 256, 0, stream>>>(ws + OQH, ws + OKH, ws + OVT, ws + OEB, ws + OAO);

  gemm_o<<<192, 256, 0, stream>>>(ws + OAO, ws + OWO, b_o, (float*)d_out);
}

// Round 6
// 308.238 us; speedup vs baseline: 1.0907x; 1.0907x over previous
//
#include <hip/hip_runtime.h>
#include <stdint.h>

// ---------------------------------------------------------------------------
// MultiHeadAttentionWithRelativePosition  (B=8, H=16, L=768, D=1024, dk=64)
// R6: R4's 128x128 GEMM tiles (known-good occupancy) + R5's XCD-local block
// decode (known-good FETCH halving). Attn/cast unchanged from R4.
// ---------------------------------------------------------------------------

#define DEVFN static __device__ __forceinline__

typedef __bf16 bf16x8 __attribute__((ext_vector_type(8)));
typedef float f32x4 __attribute__((ext_vector_type(4)));

DEVFN uint16_t f2bf(float f) {
  uint32_t u = __builtin_bit_cast(uint32_t, f);
  u += 0x7fffu + ((u >> 16) & 1u);   // RNE
  return (uint16_t)(u >> 16);
}
DEVFN bf16x8 ldg8(const uint16_t* p) { return *reinterpret_cast<const bf16x8*>(p); }

DEVFN void load_lds16(const void* g, void* l) {
  __builtin_amdgcn_global_load_lds((const __attribute__((address_space(1))) uint32_t*)g,
                                   (__attribute__((address_space(3))) uint32_t*)l,
                                   16, 0, 0);
}

DEVFN float bperm(int addr, float v) {
  return __builtin_bit_cast(float,
      __builtin_amdgcn_ds_bpermute(addr, __builtin_bit_cast(int, v)));
}

#define MFMA __builtin_amdgcn_mfma_f32_16x16x32_bf16

// ---------------- workspace layout (uint16 element offsets) ----------------
static const size_t OXQ = 0;
static const size_t OXK = 6291456;
static const size_t OXV = 12582912;
static const size_t OWQ = 18874368;
static const size_t OWK = 19922944;
static const size_t OWV = 20971520;
static const size_t OWO = 22020096;
static const size_t OEB = 23068672;   // 98304 elems (frag-linear E, 96 tiles)
static const size_t OQH = 23166976;
static const size_t OKH = 29458432;
static const size_t OVT = 35749888;
static const size_t OAO = 42041344;

// ------------------------------ cast kernel --------------------------------
__global__ __launch_bounds__(256) void cast_kernel(
    const float* __restrict__ q, const float* __restrict__ k, const float* __restrict__ v,
    const float* __restrict__ wq, const float* __restrict__ wk, const float* __restrict__ wv,
    const float* __restrict__ wo, const float* __restrict__ e, uint16_t* __restrict__ ws)
{
  constexpr int NQ = 6291456 / 4, NW = 1048576 / 4;
  constexpr int TOTM = 3 * NQ + 4 * NW;
  constexpr int NE4 = 98304 / 4;
  for (int i = blockIdx.x * blockDim.x + threadIdx.x; i < TOTM + NE4;
       i += gridDim.x * blockDim.x) {
    if (i < TOTM) {
      const float* src; uint16_t* dst; int off = i;
      if (off < NQ)              { src = q;  dst = ws + OXQ; }
      else if ((off -= NQ) < NQ) { src = k;  dst = ws + OXK; }
      else if ((off -= NQ) < NQ) { src = v;  dst = ws + OXV; }
      else if ((off -= NQ) < NW) { src = wq; dst = ws + OWQ; }
      else if ((off -= NW) < NW) { src = wk; dst = ws + OWK; }
      else if ((off -= NW) < NW) { src = wv; dst = ws + OWV; }
      else { off -= NW;            src = wo; dst = ws + OWO; }
      float4 f = reinterpret_cast<const float4*>(src)[off];
      ushort4 u;
      u.x = f2bf(f.x); u.y = f2bf(f.y); u.z = f2bf(f.z); u.w = f2bf(f.w);
      reinterpret_cast<ushort4*>(dst)[off] = u;
    } else {
      // fragment-linear E: tile tau covers rel rows [16*tau, 16*tau+15]
      int e4 = i - TOTM;
      ushort4 u;
#pragma unroll
      for (int t = 0; t < 4; ++t) {
        int o = e4 * 4 + t;
        int tau = o >> 10, r10 = o & 1023;
        int c = r10 >> 9, lane = (r10 >> 3) & 63, j = o & 7;
        int row = tau * 16 + (lane & 15);
        row = row > 1534 ? 1534 : row;
        int col = c * 32 + (lane >> 4) * 8 + j;
        ((uint16_t*)&u)[t] = f2bf(e[row * 64 + col]);
      }
      reinterpret_cast<ushort4*>(ws + OEB)[e4] = u;
    }
  }
}

// --------------------- fused QKV projection GEMM (128x128) -----------------
// 1152 blocks: [0,384) Q-proj, [384,768) K-proj, [768,1152) V^T.
// XCD-local decode: x = t&7 == XCD (grid%8 round-robin); XCD x owns 6
// consecutive tiles of the large dimension -> A-slice(1.5MB)+B(2MB) in L2.
__global__ __launch_bounds__(256, 2) void gemm_qkv(
    uint16_t* __restrict__ ws, const float* __restrict__ bq,
    const float* __restrict__ bk, const float* __restrict__ bv)
{
  constexpr int K = 1024;
  __shared__ uint16_t As[128 * 32];
  __shared__ uint16_t Bs[128 * 32];
  const int f = blockIdx.x;
  const int mode = f / 384, t = f % 384;
  const int x = t & 7, u6 = t >> 3;   // u6 in [0,48)
  const uint16_t *A, *Bw; const float* bias; uint16_t* outp;
  int m0, n0;
  if (mode == 0)      { A = ws + OXQ; Bw = ws + OWQ; bias = bq; outp = ws + OQH;
                        m0 = (x * 6 + u6 % 6) * 128; n0 = (u6 / 6) * 128; }
  else if (mode == 1) { A = ws + OXK; Bw = ws + OWK; bias = bk; outp = ws + OKH;
                        m0 = (x * 6 + u6 % 6) * 128; n0 = (u6 / 6) * 128; }
  else                { A = ws + OWV; Bw = ws + OXV; bias = bv; outp = ws + OVT;
                        n0 = (x * 6 + u6 % 6) * 128; m0 = (u6 / 6) * 128; }

  const int tid = threadIdx.x, wave = tid >> 6, lane = tid & 63;
  const int quad = lane >> 4, lc = lane & 15;
  const int wm = (wave >> 1) * 64, wn = (wave & 1) * 64;
  const int srow = lane >> 2, schunk = (lane & 3) * 8;

  f32x4 acc[4][4];
#pragma unroll
  for (int i = 0; i < 4; ++i)
#pragma unroll
    for (int j = 0; j < 4; ++j) acc[i][j] = (f32x4){0.f, 0.f, 0.f, 0.f};

  for (int k0 = 0; k0 < K; k0 += 32) {
    __syncthreads();
#pragma unroll
    for (int j = 0; j < 2; ++j) {
      int r = (wave * 2 + j) * 16 + srow;
      load_lds16(A + (size_t)(m0 + r) * K + k0 + schunk, &As[((wave * 2 + j) * 16) * 32]);
      load_lds16(Bw + (size_t)(n0 + r) * K + k0 + schunk, &Bs[((wave * 2 + j) * 16) * 32]);
    }
    __syncthreads();
    bf16x8 af[4], bfr[4];
#pragma unroll
    for (int u = 0; u < 4; ++u) {
      af[u]  = *reinterpret_cast<const bf16x8*>(&As[(wm + u * 16 + lc) * 32 + quad * 8]);
      bfr[u] = *reinterpret_cast<const bf16x8*>(&Bs[(wn + u * 16 + lc) * 32 + quad * 8]);
    }
#pragma unroll
    for (int i = 0; i < 4; ++i)
#pragma unroll
      for (int j = 0; j < 4; ++j)
        acc[i][j] = MFMA(af[i], bfr[j], acc[i][j], 0, 0, 0);
  }

  const int bM = (m0 + wm) / 768;
  const int bN = n0 / 768;
#pragma unroll
  for (int i = 0; i < 4; ++i)
#pragma unroll
    for (int j = 0; j < 4; ++j)
#pragma unroll
      for (int r = 0; r < 4; ++r) {
        int mg = m0 + wm + i * 16 + quad * 4 + r;
        int ng = n0 + wn + j * 16 + lc;
        float v = acc[i][j][r];
        if (mode == 0) {
          v = (v + bias[ng]) * 0.125f;         // 1/sqrt(64) folded into Q
          int lr = mg - bM * 768;
          int h = ng >> 6, d = ng & 63;
          outp[(((size_t)(bM * 16 + h) * 768 + lr) << 6) + d] = f2bf(v);
        } else if (mode == 1) {
          // frag-linear K
          v += bias[ng];
          int lr = mg - bM * 768;
          int h = ng >> 6, d = ng & 63;
          size_t flat = ((size_t)(bM * 16 + h) * 48 + (lr >> 4)) * 1024
                      + ((size_t)(d >> 5) << 9)
                      + ((((d >> 3) & 3) * 16 + (lr & 15)) << 3) + (d & 7);
          outp[flat] = f2bf(v);
        } else {
          // frag-linear V
          v += bias[mg];
          int lr = ng - bN * 768;
          int h = mg >> 6, d = mg & 63;
          size_t flat = (size_t)(bN * 16 + h) * 49152
                      + (size_t)(lr >> 5) * 2048 + (size_t)(d >> 4) * 512
                      + ((((lr >> 3) & 3) * 16 + (d & 15)) << 3) + (lr & 7);
          outp[flat] = f2bf(v);
        }
      }
}

// ------------------------- O-projection GEMM (128x128) ---------------------
// 384 blocks, XCD-local: XCD x owns m-tiles [6x,6x+6) -> Ao slice L2-resident.
__global__ __launch_bounds__(256, 2) void gemm_o(
    const uint16_t* __restrict__ A, const uint16_t* __restrict__ Bw,
    const float* __restrict__ bias, float* __restrict__ outp)
{
  constexpr int K = 1024;
  __shared__ uint16_t As[128 * 32];
  __shared__ uint16_t Bs[128 * 32];
  const int t = blockIdx.x;
  const int x = t & 7, u6 = t >> 3;
  const int m0 = (x * 6 + u6 % 6) * 128, n0 = (u6 / 6) * 128;

  const int tid = threadIdx.x, wave = tid >> 6, lane = tid & 63;
  const int quad = lane >> 4, lc = lane & 15;
  const int wm = (wave >> 1) * 64, wn = (wave & 1) * 64;
  const int srow = lane >> 2, schunk = (lane & 3) * 8;

  f32x4 acc[4][4];
#pragma unroll
  for (int i = 0; i < 4; ++i)
#pragma unroll
    for (int j = 0; j < 4; ++j) acc[i][j] = (f32x4){0.f, 0.f, 0.f, 0.f};

  for (int k0 = 0; k0 < K; k0 += 32) {
    __syncthreads();
#pragma unroll
    for (int j = 0; j < 2; ++j) {
      int r = (wave * 2 + j) * 16 + srow;
      load_lds16(A + (size_t)(m0 + r) * K + k0 + schunk, &As[((wave * 2 + j) * 16) * 32]);
      load_lds16(Bw + (size_t)(n0 + r) * K + k0 + schunk, &Bs[((wave * 2 + j) * 16) * 32]);
    }
    __syncthreads();
    bf16x8 af[4], bfr[4];
#pragma unroll
    for (int u = 0; u < 4; ++u) {
      af[u]  = *reinterpret_cast<const bf16x8*>(&As[(wm + u * 16 + lc) * 32 + quad * 8]);
      bfr[u] = *reinterpret_cast<const bf16x8*>(&Bs[(wn + u * 16 + lc) * 32 + quad * 8]);
    }
#pragma unroll
    for (int i = 0; i < 4; ++i)
#pragma unroll
      for (int j = 0; j < 4; ++j)
        acc[i][j] = MFMA(af[i], bfr[j], acc[i][j], 0, 0, 0);
  }

#pragma unroll
  for (int i = 0; i < 4; ++i)
#pragma unroll
    for (int j = 0; j < 4; ++j)
#pragma unroll
      for (int r = 0; r < 4; ++r) {
        int mg = m0 + wm + i * 16 + quad * 4 + r;
        int ng = n0 + wn + j * 16 + lc;
        outp[(size_t)mg * 1024 + ng] = acc[i][j][r] + bias[ng];
      }
}

// ------------------------------ attention (flash) --------------------------
// Unchanged from R4 (frag-linear K/V/E; verified).
__global__ __launch_bounds__(256, 3) void attn_kernel(
    const uint16_t* __restrict__ Qh, const uint16_t* __restrict__ KTf,
    const uint16_t* __restrict__ VTf, const uint16_t* __restrict__ Et,
    uint16_t* __restrict__ Ao)
{
  constexpr int L = 768, DK = 64;
  __shared__ uint16_t Pb[4][16][40];
  const int wave = threadIdx.x >> 6, lane = threadIdx.x & 63;
  const int quad = lane >> 4, lc = lane & 15;
  const int f = blockIdx.x, g = f >> 3;
  const int bh = (f & 7) * 16 + (g & 15);
  const int q0 = ((g >> 4) * 4 + wave) * 16;
  const int lane8 = lane * 8;

  const uint16_t* Qp = Qh + ((size_t)bh * L + q0) * DK;
  bf16x8 qf0 = ldg8(Qp + lc * DK + quad * 8);
  bf16x8 qf1 = ldg8(Qp + lc * DK + 32 + quad * 8);

  int addr_r[4]; bool sel_r[4];
#pragma unroll
  for (int r = 0; r < 4; ++r) {
    int qi = quad * 4 + r;
    int t = lc - qi + 15;
    addr_r[r] = (quad * 16 + (t & 15)) * 4;
    sel_r[r] = t >= 16;
  }

  float l_r[4] = {0.f, 0.f, 0.f, 0.f};
  f32x4 o[4];
#pragma unroll
  for (int t = 0; t < 4; ++t) o[t] = (f32x4){0.f, 0.f, 0.f, 0.f};

  const uint16_t* Kb = KTf + (size_t)bh * 48 * 1024;
  const uint16_t* Vb = VTf + (size_t)bh * 49152;
  const int taubase = 47 - (q0 >> 4);

#pragma unroll 1
  for (int kb = 0; kb < 24; ++kb) {
    const uint16_t* kp = Kb + (size_t)(2 * kb) * 1024 + lane8;
    bf16x8 k0a = ldg8(kp),        k0b = ldg8(kp + 512);
    bf16x8 k1a = ldg8(kp + 1024), k1b = ldg8(kp + 1536);
    const uint16_t* vp = Vb + (size_t)kb * 2048 + lane8;
    bf16x8 vf0 = ldg8(vp), vf1 = ldg8(vp + 512), vf2 = ldg8(vp + 1024), vf3 = ldg8(vp + 1536);

    f32x4 s0 = (f32x4){0.f, 0.f, 0.f, 0.f}, s1 = s0;
    s0 = MFMA(qf0, k0a, s0, 0, 0, 0);
    s0 = MFMA(qf1, k0b, s0, 0, 0, 0);
    s1 = MFMA(qf0, k1a, s1, 0, 0, 0);
    s1 = MFMA(qf1, k1b, s1, 0, 0, 0);

    f32x4 w[3];
#pragma unroll
    for (int ww = 0; ww < 3; ++ww) {
      const uint16_t* ep = Et + (size_t)(taubase + 2 * kb + ww) * 1024 + lane8;
      bf16x8 e0 = ldg8(ep), e1 = ldg8(ep + 512);
      f32x4 a = (f32x4){0.f, 0.f, 0.f, 0.f};
      a = MFMA(qf0, e0, a, 0, 0, 0);
      a = MFMA(qf1, e1, a, 0, 0, 0);
      w[ww] = a;
    }

#pragma unroll
    for (int r = 0; r < 4; ++r) {
      float v0a  = bperm(addr_r[r], w[0][r]);
      float vmid = bperm(addr_r[r], w[1][r]);
      float v1b  = bperm(addr_r[r], w[2][r]);
      float e0 = __expf(s0[r] + (sel_r[r] ? vmid : v0a));
      float e1 = __expf(s1[r] + (sel_r[r] ? v1b : vmid));
      l_r[r] += e0 + e1;
      int qi = quad * 4 + r;
      Pb[wave][qi][lc]      = f2bf(e0);
      Pb[wave][qi][16 + lc] = f2bf(e1);
    }

    __builtin_amdgcn_s_waitcnt(0xC07F);   // lgkmcnt(0), wave-local

    bf16x8 af = *reinterpret_cast<const bf16x8*>(&Pb[wave][lc][quad * 8]);
    o[0] = MFMA(af, vf0, o[0], 0, 0, 0);
    o[1] = MFMA(af, vf1, o[1], 0, 0, 0);
    o[2] = MFMA(af, vf2, o[2], 0, 0, 0);
    o[3] = MFMA(af, vf3, o[3], 0, 0, 0);
  }

#pragma unroll
  for (int r = 0; r < 4; ++r) {
    float l = l_r[r];
    l += __shfl_xor(l, 1, 64);
    l += __shfl_xor(l, 2, 64);
    l += __shfl_xor(l, 4, 64);
    l += __shfl_xor(l, 8, 64);
    l_r[r] = 1.0f / l;
  }

  const int b = bh >> 4, h = bh & 15;
#pragma unroll
  for (int r = 0; r < 4; ++r) {
    int qi = quad * 4 + r;
    size_t bse = ((size_t)b * L + (q0 + qi)) * 1024 + h * 64;
#pragma unroll
    for (int nt = 0; nt < 4; ++nt)
      Ao[bse + nt * 16 + lc] = f2bf(o[nt][r] * l_r[r]);
  }
}

// ------------------------------ launcher -----------------------------------
extern "C" void kernel_launch(void* const* d_in, const int* in_sizes, int n_in,
                              void* d_out, int out_size, void* d_ws, size_t ws_size,
                              hipStream_t stream) {
  const float* q   = (const float*)d_in[0];
  const float* k   = (const float*)d_in[1];
  const float* v   = (const float*)d_in[2];
  const float* b_q = (const float*)d_in[4];
  const float* b_k = (const float*)d_in[6];
  const float* b_v = (const float*)d_in[8];
  const float* b_o = (const float*)d_in[10];
  uint16_t* ws = (uint16_t*)d_ws;

  cast_kernel<<<4096, 256, 0, stream>>>(q, k, v,
      (const float*)d_in[3], (const float*)d_in[5], (const float*)d_in[7],
      (const float*)d_in[9], (const float*)d_in[11], ws);

  gemm_qkv<<<1152, 256, 0, stream>>>(ws, b_q, b_k, b_v);

  attn_kernel<<<1536, 256, 0, stream>>>(ws + OQH, ws + OKH, ws + OVT, ws + OEB, ws + OAO);

  gemm_o<<<384, 256, 0, stream>>>(ws + OAO, ws + OWO, b_o, (float*)d_out);
}